// Round 12
// baseline (333.051 us; speedup 1.0000x reference)
//
#include <hip/hip_runtime.h>
#include <hip/hip_bf16.h>

#define NN 50000
#define INF 256
#define NH 8
#define OUTF 64
#define NC 512
#define NTILES 782          // ceil(50000/64)
#define EPB 8192            // edges per sort block
#define NBK 391             // buckets: node>>7, 50000/128
#define NBX 12501           // xbar blocks in fused kernel

typedef __attribute__((ext_vector_type(8))) short bf16x8;
typedef __attribute__((ext_vector_type(4))) float f32x4;
typedef __attribute__((ext_vector_type(2))) float v2f;
typedef __attribute__((ext_vector_type(8))) float f32x8;
typedef unsigned long long u64;

__device__ __forceinline__ unsigned short f2bf(float f){
  unsigned u = __float_as_uint(f);
  u += 0x7FFFu + ((u>>16)&1u);
  return (unsigned short)(u>>16);
}

#define GLOAD_LDS16(g, s) \
  __builtin_amdgcn_global_load_lds((const __attribute__((address_space(1))) void*)(g), \
                                   (__attribute__((address_space(3))) void*)(s), 16, 0, 0)

// ---------- W -> per-head swizzled bf16 tiles (64 rows x 256 K)
__global__ __launch_bounds__(256) void k_prep_w(const float* __restrict__ W,
                                                unsigned short* __restrict__ Wt){
  const int tid = threadIdx.x;
  const int r = tid>>2, cb = (tid&3)*64;
  char* tile = (char*)(Wt + (size_t)blockIdx.x*16384);
  const float* Wr = W + ((long)blockIdx.x*64 + r)*INF;
#pragma unroll
  for (int i=0;i<16;i++){
    int c = cb + i*4;
    float4 v = *(const float4*)(Wr + c);
    ushort4 b; b.x=f2bf(v.x); b.y=f2bf(v.y); b.z=f2bf(v.z); b.w=f2bf(v.w);
    int addr = r*512 + ((((c>>3) ^ (r&7)))<<4) + ((c&7)<<1);
    *(ushort4*)(tile + addr) = b;
  }
}

// ---------- atil[h][f] = sum_o W[h*64+o][f] * a_r[h][o]
__global__ void k_atil(const float* __restrict__ W, const float* __restrict__ As,
                       float* __restrict__ atil){
  const int h = blockIdx.x, f = threadIdx.x;
  float s = 0.f;
  for (int o=0;o<64;o++) s += W[((long)h*64+o)*INF + f] * As[h*128 + 64 + o];
  atil[h*256 + f] = s;
}

// ---------- fused: per-node xb/eAr  +  bucket histogram of src
__global__ __launch_bounds__(256) void k_xbar_bhist(const float* __restrict__ x,
                                                    const float* __restrict__ atil,
                                                    unsigned short* __restrict__ xb,
                                                    float* __restrict__ eAr,
                                                    const int* __restrict__ src,
                                                    int* __restrict__ M,
                                                    int E, int NB){
  __shared__ int hh[NBK];
  const int tid = threadIdx.x;
  if (blockIdx.x >= NBX){
    const int b = blockIdx.x - NBX;
    for (int i=tid;i<NBK;i+=256) hh[i]=0;
    __syncthreads();
    const int base = b*EPB;
    const int lim = min(E-base, EPB);
    for (int i=tid;i<lim;i+=256) atomicAdd(&hh[src[base+i]>>7], 1);
    __syncthreads();
    for (int i=tid;i<NBK;i+=256) M[(long)i*NB + b] = hh[i];
    return;
  }
  const int w = tid>>6, l = tid&63;
  const long n = (long)blockIdx.x*4 + w;
  if (n > NN) return;
  if (n == NN){   // zero sentinel row
    uint2 z; z.x=0; z.y=0;
    *(uint2*)((char*)xb + (size_t)n*512 + l*8) = z;
    if (l < 8) eAr[n*NH + l] = 0.f;
    return;
  }
  float4 v = *(const float4*)(x + n*INF + l*4);
  uint2 d;
  d.x = (unsigned)f2bf(v.x) | ((unsigned)f2bf(v.y)<<16);
  d.y = (unsigned)f2bf(v.z) | ((unsigned)f2bf(v.w)<<16);
  *(uint2*)((char*)xb + (size_t)n*512 + l*8) = d;
  float p[8];
#pragma unroll
  for (int h=0;h<8;h++){
    float4 a = *(const float4*)(atil + h*256 + l*4);
    p[h] = v.x*a.x + v.y*a.y + v.z*a.z + v.w*a.w;
  }
#pragma unroll
  for (int off=1; off<64; off<<=1){
#pragma unroll
    for (int h=0;h<8;h++) p[h] += __shfl_xor(p[h], off, 64);
  }
  if (l < 8){
    float e = p[0];
#pragma unroll
    for (int h=1;h<8;h++) if (l==h) e = p[h];
    eAr[n*NH + l] = __expf(e);
  }
}

// per-bucket exclusive scan over blocks (in place) + bucket totals
__global__ __launch_bounds__(256) void k_bscan(int* __restrict__ M,
                                               int* __restrict__ tot, int NB){
  __shared__ int lds[256];
  const int k = blockIdx.x, tid = threadIdx.x;
  int v = (tid<NB) ? M[(long)k*NB+tid] : 0;
  const int orig = v;
  lds[tid]=v; __syncthreads();
  for (int off=1; off<256; off<<=1){
    int a = (tid>=off)? lds[tid-off] : 0;
    __syncthreads(); lds[tid]+=a; __syncthreads();
  }
  if (tid<NB) M[(long)k*NB+tid] = lds[tid]-orig;
  if (tid==255) tot[k] = lds[255];
}

// generic small exclusive scan (n < 512), out[0..n], out[n]=total
__global__ __launch_bounds__(512) void k_sscan(const int* __restrict__ in,
                                               int* __restrict__ out, int n){
  __shared__ int lds[512];
  const int tid = threadIdx.x;
  int v = (tid<n)? in[tid] : 0;
  const int orig = v;
  lds[tid]=v; __syncthreads();
  for (int off=1; off<512; off<<=1){
    int a = (tid>=off)? lds[tid-off] : 0;
    __syncthreads(); lds[tid]+=a; __syncthreads();
  }
  if (tid<=n) out[tid] = lds[tid]-orig;
}

// bucket scatter of (src,dst) pairs via LDS cursors
__global__ __launch_bounds__(256) void k_bscat(const int* __restrict__ src,
                                               const int* __restrict__ dst,
                                               const int* __restrict__ M,
                                               const int* __restrict__ bOff,
                                               u64* __restrict__ ebuf,
                                               int E, int NB){
  __shared__ int cur[NBK];
  const int tid = threadIdx.x, b = blockIdx.x;
  for (int i=tid;i<NBK;i+=256) cur[i] = bOff[i] + M[(long)i*NB + b];
  __syncthreads();
  const int base = b*EPB;
  const int lim = min(E-base, EPB);
  for (int i=tid;i<lim;i+=256){
    int s = src[base+i], d = dst[base+i];
    int p = atomicAdd(&cur[s>>7], 1);
    ebuf[p] = ((u64)(unsigned)d<<32) | (unsigned)s;
  }
}

// per-bucket node counts + padded(8) bucket total
__global__ __launch_bounds__(256) void k_bcnt2(const u64* __restrict__ ebuf,
                                               const int* __restrict__ bOff,
                                               int* __restrict__ cnt,
                                               int* __restrict__ pbTot){
  __shared__ int h[128];
  __shared__ int ps[128];
  const int k = blockIdx.x, tid = threadIdx.x;
  if (tid<128) h[tid]=0;
  __syncthreads();
  const int beg = bOff[k], end = bOff[k+1];
  for (int i=beg+tid; i<end; i+=256)
    atomicAdd(&h[(int)(unsigned)ebuf[i] & 127], 1);
  __syncthreads();
  if (tid<128){
    cnt[(k<<7)+tid] = h[tid];
    ps[tid] = (h[tid]+7)&~7;
  }
  __syncthreads();
  for (int off=64; off>0; off>>=1){
    if (tid<off) ps[tid] += ps[tid+off];
    __syncthreads();
  }
  if (tid==0) pbTot[k] = ps[0];
}

// finalize: local padded scan -> row_ptr, scatter, padfill — all per bucket
__global__ __launch_bounds__(256) void k_final(const u64* __restrict__ ebuf,
                                               const int* __restrict__ bOff,
                                               const int* __restrict__ cnt,
                                               const int* __restrict__ pbOff,
                                               int* __restrict__ row_ptr,
                                               int* __restrict__ col){
  __shared__ int s[128];
  __shared__ int cur[128];
  __shared__ int pend[128];
  const int k = blockIdx.x, tid = threadIdx.x;
  int c = 0, pc = 0;
  if (tid<128){
    c = cnt[(k<<7)+tid];
    pc = (c+7)&~7;
    s[tid] = pc;
  }
  __syncthreads();
  for (int off=1; off<128; off<<=1){
    int a = (tid>=off && tid<128)? s[tid-off] : 0;
    __syncthreads();
    if (tid<128) s[tid] += a;
    __syncthreads();
  }
  const int base = pbOff[k];
  if (tid<128){
    int rp = base + s[tid] - pc;
    row_ptr[(k<<7)+tid] = rp;
    cur[tid] = rp;
    pend[tid] = rp + pc;
  }
  __syncthreads();
  const int beg = bOff[k], end = bOff[k+1];
  for (int i=beg+tid; i<end; i+=256){
    u64 e = ebuf[i];
    int sn = (int)(unsigned)e;
    int d  = (int)(e>>32);
    int p = atomicAdd(&cur[sn&127], 1);
    col[p] = d;
  }
  __syncthreads();
  if (tid<128){
    for (int i=cur[tid]; i<pend[tid]; i++) col[i] = NN;  // sentinel
  }
}

// ---------------- aggregation: XCD-sharded feature halves
// block b: feature-half = b&1 (maps to even/odd XCD via %8 round-robin),
// 4 waves handle 4 consecutive nodes' half-rows.
__global__ __launch_bounds__(256) void k_aggr2(const int* __restrict__ row_ptr,
                                               const int* __restrict__ col,
                                               const unsigned short* __restrict__ xb,
                                               const float* __restrict__ eAr,
                                               unsigned short* __restrict__ g,
                                               float* __restrict__ den,
                                               int tile0){
  const int tid = threadIdx.x, l = tid&63;
  const int wv = tid>>6;               // 0..3
  const int fh = blockIdx.x & 1;       // feature half -> XCD parity
  const long n = (long)tile0*64 + (blockIdx.x>>1)*4 + wv;
  if (n >= NN) return;
  const int beg = __builtin_amdgcn_readfirstlane(row_ptr[n]);
  const int end = __builtin_amdgcn_readfirstlane(row_ptr[n+1]);
  const char* xbp = (const char*)xb + fh*256;   // this wave's feature-half base
  v2f acc[8] = {};
  float dnl = 0.f;
  const long l4 = (long)l*4;
  const int lw = l&7;

  for (int i=beg; i<end; i+=8){
    int cc[8];
#pragma unroll
    for (int e=0;e<8;e++) cc[e] = __builtin_amdgcn_readfirstlane(col[i+e]);
    unsigned q[8];
#pragma unroll
    for (int e=0;e<8;e++) q[e] = *(const unsigned*)(xbp + (size_t)cc[e]*512 + l4);
    float wl[8];
#pragma unroll
    for (int e=0;e<8;e++) wl[e] = eAr[(size_t)cc[e]*NH + lw];
#pragma unroll
    for (int e=0;e<8;e++) dnl += wl[e];
#pragma unroll
    for (int e=0;e<8;e++){
      f32x8 wv8 = *(const f32x8*)(eAr + (size_t)cc[e]*NH);  // uniform -> scalar load
      v2f f01;
      f01.x = __uint_as_float(q[e]<<16);
      f01.y = __uint_as_float(q[e]&0xffff0000u);
#pragma unroll
      for (int h=0;h<8;h++){
        v2f w2; w2.x = wv8[h]; w2.y = wv8[h];
        acc[h] = __builtin_elementwise_fma(w2, f01, acc[h]);
      }
    }
  }

  // writeout: lane holds features f0 = fh*128 + l*2, f0+1 (bf16 pair = 4B)
  const int lt = (int)(n>>6) - tile0;
  const int r  = (int)(n&63);
  const int f0 = fh*128 + l*2;
  char* tb = (char*)g + (size_t)lt*262144 + r*512
           + ((((f0>>3) ^ (r&7)))<<4) + ((f0&7)<<1);
#pragma unroll
  for (int h=0;h<8;h++){
    unsigned d = (unsigned)f2bf(acc[h].x) | ((unsigned)f2bf(acc[h].y)<<16);
    *(unsigned*)(tb + h*32768) = d;
  }
  if (fh==0 && l < 8) den[n*NH + l] = dnl;
}

// ---------------- per-head GEMM: out[n, h*64+o] = elu( (g_h[n] . W_h[o]) / den )
__global__ __launch_bounds__(256) void k_gemm2(const unsigned short* __restrict__ g,
                                               const unsigned short* __restrict__ Wt,
                                               const float* __restrict__ den,
                                               float* __restrict__ out,
                                               int tile0){
  __shared__ unsigned short As[16384];
  __shared__ unsigned short Bs[16384];
  __shared__ float linv[64];
  const int tid = threadIdx.x, w = tid>>6, l = tid&63;
  const int brow = tile0 + blockIdx.x;
  const int h = blockIdx.y;
  {
    const char* srcA = (const char*)g + (size_t)blockIdx.x*262144 + h*32768 + w*8192 + l*16;
    char* dstA = (char*)As + w*8192;
#pragma unroll
    for (int k=0;k<8;k++) GLOAD_LDS16(srcA + k*1024, dstA + k*1024);
    const char* srcB = (const char*)Wt + (size_t)h*32768 + w*8192 + l*16;
    char* dstB = (char*)Bs + w*8192;
#pragma unroll
    for (int k=0;k<8;k++) GLOAD_LDS16(srcB + k*1024, dstB + k*1024);
  }
  if (tid < 64){
    long gr = (long)brow*64 + tid;
    float dv = (gr < NN) ? den[gr*NH + h] : 1.f;
    linv[tid] = dv > 0.f ? 1.f/dv : 0.f;
  }
  asm volatile("s_waitcnt vmcnt(0)");
  __syncthreads();

  const int col = w*16 + (l&15);
  f32x4 acc[4] = {};
#pragma unroll
  for (int ks=0; ks<8; ks++){
    int chunkB = (ks*4 + (l>>4)) ^ (col&7);
    bf16x8 bfrag = *(const bf16x8*)((char*)Bs + col*512 + (chunkB<<4));
#pragma unroll
    for (int mt=0; mt<4; mt++){
      int ar_ = mt*16 + (l&15);
      int chunkA = (ks*4 + (l>>4)) ^ (ar_&7);
      bf16x8 afrag = *(const bf16x8*)((char*)As + ar_*512 + (chunkA<<4));
      acc[mt] = __builtin_amdgcn_mfma_f32_16x16x32_bf16(afrag, bfrag, acc[mt], 0,0,0);
    }
  }
#pragma unroll
  for (int mt=0; mt<4; mt++){
#pragma unroll
    for (int j=0;j<4;j++){
      int r = mt*16 + (l>>4)*4 + j;
      long gr = (long)brow*64 + r;
      if (gr < NN){
        float v = acc[mt][j] * linv[r];
        out[gr*NC + h*64 + col] = v>0.f ? v : expm1f(v);
      }
    }
  }
}

extern "C" void kernel_launch(void* const* d_in, const int* in_sizes, int n_in,
                              void* d_out, int out_size, void* d_ws, size_t ws_size,
                              hipStream_t stream){
  const float* x   = (const float*)d_in[0];
  const int*   src = (const int*)d_in[1];
  const int*   dst = (const int*)d_in[2];
  const float* Ws  = (const float*)d_in[3];
  const float* Av  = (const float*)d_in[4];
  const int E = in_sizes[1];
  const int NB = (E + EPB - 1) / EPB;

  char* ws = (char*)d_ws;
  size_t off = 0;
  auto alloc = [&](size_t bytes)->void*{
    void* p = ws + off; off += (bytes + 255) & ~(size_t)255; return p;
  };
  unsigned short* xb   = (unsigned short*)alloc((size_t)50048*512);
  float* eAr           = (float*)alloc((size_t)50048*NH*4);
  float* atil          = (float*)alloc(8*256*4);
  float* den           = (float*)alloc((size_t)50048*NH*4);
  unsigned short* Wt   = (unsigned short*)alloc((size_t)8*32768);
  int*   cnt           = (int*)alloc(50304*4);
  int*   row_ptr       = (int*)alloc(50304*4);
  int*   M             = (int*)alloc((size_t)NBK*256*4);
  int*   tot           = (int*)alloc(512*4);
  int*   bOff          = (int*)alloc(512*4);
  int*   pbTot         = (int*)alloc(512*4);
  int*   pbOff         = (int*)alloc(512*4);
  int*   col           = (int*)alloc(((size_t)E + 8*50048 + 64)*4);

  // adaptive g: as many 64-row tiles (256KB each) as workspace allows
  size_t remain = (ws_size > off + 256) ? (ws_size - off - 256) : 0;
  int chunk = (int)(remain / 262144);
  if (chunk > NTILES) chunk = NTILES;
  if (chunk < 49) chunk = 49;            // ebuf (E*8 bytes) must fit in g alias
  unsigned short* g = (unsigned short*)alloc((size_t)chunk*262144);
  u64* ebuf = (u64*)g;                   // dead before first g write

  k_prep_w<<<8,256,0,stream>>>(Ws, Wt);
  k_atil<<<8,256,0,stream>>>(Ws, Av, atil);
  k_xbar_bhist<<<NBX+NB,256,0,stream>>>(x, atil, xb, eAr, src, M, E, NB);

  k_bscan<<<NBK,256,0,stream>>>(M, tot, NB);
  k_sscan<<<1,512,0,stream>>>(tot, bOff, NBK);
  k_bscat<<<NB,256,0,stream>>>(src, dst, M, bOff, ebuf, E, NB);
  k_bcnt2<<<NBK,256,0,stream>>>(ebuf, bOff, cnt, pbTot);
  k_sscan<<<1,512,0,stream>>>(pbTot, pbOff, NBK);
  k_final<<<NBK,256,0,stream>>>(ebuf, bOff, cnt, pbOff, row_ptr, col);

  int tile0 = 0;
  while (tile0 < NTILES){
    int tiles = NTILES - tile0 < chunk ? NTILES - tile0 : chunk;
    k_aggr2<<<tiles*32,256,0,stream>>>(row_ptr, col, xb, eAr, g, den, tile0);
    k_gemm2<<<dim3(tiles,8),256,0,stream>>>(g, Wt, den, (float*)d_out, tile0);
    tile0 += tiles;
  }
}

// Round 14
// 310.984 us; speedup vs baseline: 1.0710x; 1.0710x over previous
//
#include <hip/hip_runtime.h>
#include <hip/hip_bf16.h>

#define NN 50000
#define INF 256
#define NH 8
#define OUTF 64
#define NC 512
#define NTILES 782          // ceil(50000/64)
#define EPB 8192            // edges per sort block
#define NBK 391             // buckets: node>>7, 50000/128
#define NBX 12501           // xbar block count

typedef __attribute__((ext_vector_type(8))) short bf16x8;
typedef __attribute__((ext_vector_type(4))) float f32x4;
typedef __attribute__((ext_vector_type(2))) float v2f;
typedef __attribute__((ext_vector_type(8))) float f32x8;

__device__ __forceinline__ unsigned short f2bf(float f){
  unsigned u = __float_as_uint(f);
  u += 0x7FFFu + ((u>>16)&1u);
  return (unsigned short)(u>>16);
}

#define GLOAD_LDS16(g, s) \
  __builtin_amdgcn_global_load_lds((const __attribute__((address_space(1))) void*)(g), \
                                   (__attribute__((address_space(3))) void*)(s), 16, 0, 0)

// ---------- atil[h][f] = sum_o W[h*64+o][f] * a_r[h][o]  (runs FIRST)
__global__ void k_atil(const float* __restrict__ W, const float* __restrict__ As,
                       float* __restrict__ atil){
  const int h = blockIdx.x, f = threadIdx.x;
  float s = 0.f;
  for (int o=0;o<64;o++) s += W[((long)h*64+o)*INF + f] * As[h*128 + 64 + o];
  atil[h*256 + f] = s;
}

// ---------- fused front-end: prep_w | bhist | xbar (atil from prior kernel)
__global__ __launch_bounds__(256) void k_front(const float* __restrict__ x,
                                               const float* __restrict__ W,
                                               unsigned short* __restrict__ Wt,
                                               const float* __restrict__ atil,
                                               unsigned short* __restrict__ xb,
                                               float* __restrict__ eAr,
                                               const int* __restrict__ src,
                                               int* __restrict__ M,
                                               int E, int NB){
  __shared__ int hh[NBK];
  const int tid = threadIdx.x;
  const int bid = blockIdx.x;
  if (bid < 8){
    const int r = tid>>2, cb = (tid&3)*64;
    char* tile = (char*)(Wt + (size_t)bid*16384);
    const float* Wr = W + ((long)bid*64 + r)*INF;
#pragma unroll
    for (int i=0;i<16;i++){
      int c = cb + i*4;
      float4 v = *(const float4*)(Wr + c);
      ushort4 b; b.x=f2bf(v.x); b.y=f2bf(v.y); b.z=f2bf(v.z); b.w=f2bf(v.w);
      int addr = r*512 + ((((c>>3) ^ (r&7)))<<4) + ((c&7)<<1);
      *(ushort4*)(tile + addr) = b;
    }
    return;
  }
  if (bid < 8+NB){
    const int b = bid-8;
    for (int i=tid;i<NBK;i+=256) hh[i]=0;
    __syncthreads();
    const int base = b*EPB;
    const int lim = min(E-base, EPB);
    for (int i=tid;i<lim;i+=256) atomicAdd(&hh[src[base+i]>>7], 1);
    __syncthreads();
    for (int i=tid;i<NBK;i+=256) M[(long)i*NB + b] = hh[i];
    return;
  }
  const int w = tid>>6, l = tid&63;
  const long n = (long)(bid-8-NB)*4 + w;
  if (n > NN) return;
  if (n == NN){
    uint2 z; z.x=0; z.y=0;
    *(uint2*)((char*)xb + (size_t)n*512 + l*8) = z;
    if (l < 8) eAr[n*NH + l] = 0.f;
    return;
  }
  float4 v = *(const float4*)(x + n*INF + l*4);
  uint2 d;
  d.x = (unsigned)f2bf(v.x) | ((unsigned)f2bf(v.y)<<16);
  d.y = (unsigned)f2bf(v.z) | ((unsigned)f2bf(v.w)<<16);
  *(uint2*)((char*)xb + (size_t)n*512 + l*8) = d;
  float p[8];
#pragma unroll
  for (int h=0;h<8;h++){
    float4 a = *(const float4*)(atil + h*256 + l*4);
    p[h] = v.x*a.x + v.y*a.y + v.z*a.z + v.w*a.w;
  }
#pragma unroll
  for (int off=1; off<64; off<<=1){
#pragma unroll
    for (int h=0;h<8;h++) p[h] += __shfl_xor(p[h], off, 64);
  }
  if (l < 8){
    float e = p[0];
#pragma unroll
    for (int h=1;h<8;h++) if (l==h) e = p[h];
    eAr[n*NH + l] = __expf(e);
  }
}

// per-bucket exclusive scan over blocks (in place) + bucket totals
__global__ __launch_bounds__(256) void k_bscan(int* __restrict__ M,
                                               int* __restrict__ tot, int NB){
  __shared__ int lds[256];
  const int k = blockIdx.x, tid = threadIdx.x;
  int v = (tid<NB) ? M[(long)k*NB+tid] : 0;
  const int orig = v;
  lds[tid]=v; __syncthreads();
  for (int off=1; off<256; off<<=1){
    int a = (tid>=off)? lds[tid-off] : 0;
    __syncthreads(); lds[tid]+=a; __syncthreads();
  }
  if (tid<NB) M[(long)k*NB+tid] = lds[tid]-orig;
  if (tid==255) tot[k] = lds[255];
}

// generic small exclusive scan (n < 512), out[0..n], out[n]=total
__global__ __launch_bounds__(512) void k_sscan(const int* __restrict__ in,
                                               int* __restrict__ out, int n){
  __shared__ int lds[512];
  const int tid = threadIdx.x;
  int v = (tid<n)? in[tid] : 0;
  const int orig = v;
  lds[tid]=v; __syncthreads();
  for (int off=1; off<512; off<<=1){
    int a = (tid>=off)? lds[tid-off] : 0;
    __syncthreads(); lds[tid]+=a; __syncthreads();
  }
  if (tid<=n) out[tid] = lds[tid]-orig;
}

// bucket scatter of (src,dst) via LDS cursors — u32 payload: dst<<7 | src&127
__global__ __launch_bounds__(256) void k_bscat(const int* __restrict__ src,
                                               const int* __restrict__ dst,
                                               const int* __restrict__ M,
                                               const int* __restrict__ bOff,
                                               unsigned* __restrict__ ebuf,
                                               int E, int NB){
  __shared__ int cur[NBK];
  const int tid = threadIdx.x, b = blockIdx.x;
  for (int i=tid;i<NBK;i+=256) cur[i] = bOff[i] + M[(long)i*NB + b];
  __syncthreads();
  const int base = b*EPB;
  const int lim = min(E-base, EPB);
  for (int i=tid;i<lim;i+=256){
    int s = src[base+i], d = dst[base+i];
    int p = atomicAdd(&cur[s>>7], 1);
    ebuf[p] = ((unsigned)d<<7) | (unsigned)(s&127);
  }
}

// per-bucket node counts + padded(8) bucket total
__global__ __launch_bounds__(256) void k_bcnt2(const unsigned* __restrict__ ebuf,
                                               const int* __restrict__ bOff,
                                               int* __restrict__ cnt,
                                               int* __restrict__ pbTot){
  __shared__ int h[128];
  __shared__ int ps[128];
  const int k = blockIdx.x, tid = threadIdx.x;
  if (tid<128) h[tid]=0;
  __syncthreads();
  const int beg = bOff[k], end = bOff[k+1];
  for (int i=beg+tid; i<end; i+=256)
    atomicAdd(&h[(int)(ebuf[i] & 127u)], 1);
  __syncthreads();
  if (tid<128){
    cnt[(k<<7)+tid] = h[tid];
    ps[tid] = (h[tid]+7)&~7;
  }
  __syncthreads();
  for (int off=64; off>0; off>>=1){
    if (tid<off) ps[tid] += ps[tid+off];
    __syncthreads();
  }
  if (tid==0) pbTot[k] = ps[0];
}

// finalize: row_ptr + scatter + padfill per bucket
__global__ __launch_bounds__(256) void k_final(const unsigned* __restrict__ ebuf,
                                               const int* __restrict__ bOff,
                                               const int* __restrict__ cnt,
                                               const int* __restrict__ pbOff,
                                               int* __restrict__ row_ptr,
                                               int* __restrict__ col){
  __shared__ int s[128];
  __shared__ int cur[128];
  __shared__ int pend[128];
  const int k = blockIdx.x, tid = threadIdx.x;
  int c = 0, pc = 0;
  if (tid<128){
    c = cnt[(k<<7)+tid];
    pc = (c+7)&~7;
    s[tid] = pc;
  }
  __syncthreads();
  for (int off=1; off<128; off<<=1){
    int a = (tid>=off && tid<128)? s[tid-off] : 0;
    __syncthreads();
    if (tid<128) s[tid] += a;
    __syncthreads();
  }
  const int base = pbOff[k];
  if (tid<128){
    int rp = base + s[tid] - pc;
    row_ptr[(k<<7)+tid] = rp;
    cur[tid] = rp;
    pend[tid] = rp + pc;
  }
  __syncthreads();
  const int beg = bOff[k], end = bOff[k+1];
  for (int i=beg+tid; i<end; i+=256){
    unsigned e = ebuf[i];
    int p = atomicAdd(&cur[e & 127u], 1);
    col[p] = (int)(e>>7);
  }
  __syncthreads();
  if (tid<128){
    for (int i=cur[tid]; i<pend[tid]; i++) col[i] = NN;  // sentinel
  }
}

// ---------------- aggregation: half-row waves (2 waves/node), packed FMA
__global__ __launch_bounds__(256) void k_aggr2(const int* __restrict__ row_ptr,
                                               const int* __restrict__ col,
                                               const unsigned short* __restrict__ xb,
                                               const float* __restrict__ eAr,
                                               unsigned short* __restrict__ g,
                                               float* __restrict__ den,
                                               int tile0){
  const int tid = threadIdx.x, l = tid&63;
  const int wv = tid>>6;               // 0..3
  const int fh = wv&1;                 // feature half
  const long n = (long)tile0*64 + blockIdx.x*2 + (wv>>1);
  if (n >= NN) return;
  const int beg = __builtin_amdgcn_readfirstlane(row_ptr[n]);
  const int end = __builtin_amdgcn_readfirstlane(row_ptr[n+1]);
  const char* xbp = (const char*)xb + fh*256;
  v2f acc[8] = {};
  float dnl = 0.f;
  const long l4 = (long)l*4;
  const int lw = l&7;

  for (int i=beg; i<end; i+=8){
    int cc[8];
#pragma unroll
    for (int e=0;e<8;e++) cc[e] = __builtin_amdgcn_readfirstlane(col[i+e]);
    unsigned q[8];
#pragma unroll
    for (int e=0;e<8;e++) q[e] = *(const unsigned*)(xbp + (size_t)cc[e]*512 + l4);
    float wl[8];
#pragma unroll
    for (int e=0;e<8;e++) wl[e] = eAr[(size_t)cc[e]*NH + lw];
#pragma unroll
    for (int e=0;e<8;e++) dnl += wl[e];
#pragma unroll
    for (int e=0;e<8;e++){
      f32x8 wv8 = *(const f32x8*)(eAr + (size_t)cc[e]*NH);
      v2f f01;
      f01.x = __uint_as_float(q[e]<<16);
      f01.y = __uint_as_float(q[e]&0xffff0000u);
#pragma unroll
      for (int h=0;h<8;h++){
        v2f w2; w2.x = wv8[h]; w2.y = wv8[h];
        acc[h] = __builtin_elementwise_fma(w2, f01, acc[h]);
      }
    }
  }

  const int lt = (int)(n>>6) - tile0;
  const int r  = (int)(n&63);
  const int f0 = fh*128 + l*2;
  char* tb = (char*)g + (size_t)lt*262144 + r*512
           + ((((f0>>3) ^ (r&7)))<<4) + ((f0&7)<<1);
#pragma unroll
  for (int h=0;h<8;h++){
    unsigned d = (unsigned)f2bf(acc[h].x) | ((unsigned)f2bf(acc[h].y)<<16);
    *(unsigned*)(tb + h*32768) = d;
  }
  if (fh==0 && l < 8) den[n*NH + l] = dnl;
}

// ---------------- per-head GEMM: out[n, h*64+o] = elu( (g_h[n] . W_h[o]) / den )
__global__ __launch_bounds__(256) void k_gemm2(const unsigned short* __restrict__ g,
                                               const unsigned short* __restrict__ Wt,
                                               const float* __restrict__ den,
                                               float* __restrict__ out,
                                               int tile0){
  __shared__ unsigned short As[16384];
  __shared__ unsigned short Bs[16384];
  __shared__ float linv[64];
  const int tid = threadIdx.x, w = tid>>6, l = tid&63;
  const int brow = tile0 + blockIdx.x;
  const int h = blockIdx.y;
  {
    const char* srcA = (const char*)g + (size_t)blockIdx.x*262144 + h*32768 + w*8192 + l*16;
    char* dstA = (char*)As + w*8192;
#pragma unroll
    for (int k=0;k<8;k++) GLOAD_LDS16(srcA + k*1024, dstA + k*1024);
    const char* srcB = (const char*)Wt + (size_t)h*32768 + w*8192 + l*16;
    char* dstB = (char*)Bs + w*8192;
#pragma unroll
    for (int k=0;k<8;k++) GLOAD_LDS16(srcB + k*1024, dstB + k*1024);
  }
  if (tid < 64){
    long gr = (long)brow*64 + tid;
    float dv = (gr < NN) ? den[gr*NH + h] : 1.f;
    linv[tid] = dv > 0.f ? 1.f/dv : 0.f;
  }
  asm volatile("s_waitcnt vmcnt(0)");
  __syncthreads();

  const int col = w*16 + (l&15);
  f32x4 acc[4] = {};
#pragma unroll
  for (int ks=0; ks<8; ks++){
    int chunkB = (ks*4 + (l>>4)) ^ (col&7);
    bf16x8 bfrag = *(const bf16x8*)((char*)Bs + col*512 + (chunkB<<4));
#pragma unroll
    for (int mt=0; mt<4; mt++){
      int ar_ = mt*16 + (l&15);
      int chunkA = (ks*4 + (l>>4)) ^ (ar_&7);
      bf16x8 afrag = *(const bf16x8*)((char*)As + ar_*512 + (chunkA<<4));
      acc[mt] = __builtin_amdgcn_mfma_f32_16x16x32_bf16(afrag, bfrag, acc[mt], 0,0,0);
    }
  }
#pragma unroll
  for (int mt=0; mt<4; mt++){
#pragma unroll
    for (int j=0;j<4;j++){
      int r = mt*16 + (l>>4)*4 + j;
      long gr = (long)brow*64 + r;
      if (gr < NN){
        float v = acc[mt][j] * linv[r];
        out[gr*NC + h*64 + col] = v>0.f ? v : expm1f(v);
      }
    }
  }
}

extern "C" void kernel_launch(void* const* d_in, const int* in_sizes, int n_in,
                              void* d_out, int out_size, void* d_ws, size_t ws_size,
                              hipStream_t stream){
  const float* x   = (const float*)d_in[0];
  const int*   src = (const int*)d_in[1];
  const int*   dst = (const int*)d_in[2];
  const float* Ws  = (const float*)d_in[3];
  const float* Av  = (const float*)d_in[4];
  const int E = in_sizes[1];
  const int NB = (E + EPB - 1) / EPB;

  char* ws = (char*)d_ws;
  size_t off = 0;
  auto alloc = [&](size_t bytes)->void*{
    void* p = ws + off; off += (bytes + 255) & ~(size_t)255; return p;
  };
  unsigned short* xb   = (unsigned short*)alloc((size_t)50048*512);
  float* eAr           = (float*)alloc((size_t)50048*NH*4);
  float* atil          = (float*)alloc(8*256*4);
  float* den           = (float*)alloc((size_t)50048*NH*4);
  unsigned short* Wt   = (unsigned short*)alloc((size_t)8*32768);
  int*   cnt           = (int*)alloc(50304*4);
  int*   row_ptr       = (int*)alloc(50304*4);
  int*   M             = (int*)alloc((size_t)NBK*256*4);
  int*   tot           = (int*)alloc(512*4);
  int*   bOff          = (int*)alloc(512*4);
  int*   pbTot         = (int*)alloc(512*4);
  int*   pbOff         = (int*)alloc(512*4);
  int*   col           = (int*)alloc(((size_t)E + 8*50048 + 64)*4);

  size_t remain = (ws_size > off + 256) ? (ws_size - off - 256) : 0;
  int chunk = (int)(remain / 262144);
  if (chunk > NTILES) chunk = NTILES;
  if (chunk < 25) chunk = 25;            // ebuf (E*4 bytes) must fit in g alias
  unsigned short* g = (unsigned short*)alloc((size_t)chunk*262144);
  unsigned* ebuf = (unsigned*)g;         // dead before first g write

  k_atil<<<8,256,0,stream>>>(Ws, Av, atil);
  k_front<<<8+NB+NBX,256,0,stream>>>(x, Ws, Wt, atil, xb, eAr, src, M, E, NB);
  k_bscan<<<NBK,256,0,stream>>>(M, tot, NB);
  k_sscan<<<1,512,0,stream>>>(tot, bOff, NBK);
  k_bscat<<<NB,256,0,stream>>>(src, dst, M, bOff, ebuf, E, NB);
  k_bcnt2<<<NBK,256,0,stream>>>(ebuf, bOff, cnt, pbTot);
  k_sscan<<<1,512,0,stream>>>(pbTot, pbOff, NBK);
  k_final<<<NBK,256,0,stream>>>(ebuf, bOff, cnt, pbOff, row_ptr, col);

  int tile0 = 0;
  while (tile0 < NTILES){
    int tiles = NTILES - tile0 < chunk ? NTILES - tile0 : chunk;
    k_aggr2<<<tiles*32,256,0,stream>>>(row_ptr, col, xb, eAr, g, den, tile0);
    k_gemm2<<<dim3(tiles,8),256,0,stream>>>(g, Wt, den, (float*)d_out, tile0);
    tile0 += tiles;
  }
}

// Round 15
// 310.433 us; speedup vs baseline: 1.0729x; 1.0018x over previous
//
#include <hip/hip_runtime.h>
#include <hip/hip_bf16.h>

#define NN 50000
#define INF 256
#define NH 8
#define OUTF 64
#define NC 512
#define NTILES 782          // ceil(50000/64)
#define EPB 8192            // edges per sort block
#define NBK 391             // buckets: node>>7, 50000/128
#define NBX 12501           // xbar block count

typedef __attribute__((ext_vector_type(8))) short bf16x8;
typedef __attribute__((ext_vector_type(4))) float f32x4;
typedef __attribute__((ext_vector_type(2))) float v2f;
typedef __attribute__((ext_vector_type(8))) float f32x8;

__device__ __forceinline__ unsigned short f2bf(float f){
  unsigned u = __float_as_uint(f);
  u += 0x7FFFu + ((u>>16)&1u);
  return (unsigned short)(u>>16);
}

#define GLOAD_LDS16(g, s) \
  __builtin_amdgcn_global_load_lds((const __attribute__((address_space(1))) void*)(g), \
                                   (__attribute__((address_space(3))) void*)(s), 16, 0, 0)

// ---------- atil[h][f] = sum_o W[h*64+o][f] * a_r[h][o]  (runs FIRST)
__global__ void k_atil(const float* __restrict__ W, const float* __restrict__ As,
                       float* __restrict__ atil){
  const int h = blockIdx.x, f = threadIdx.x;
  float s = 0.f;
  for (int o=0;o<64;o++) s += W[((long)h*64+o)*INF + f] * As[h*128 + 64 + o];
  atil[h*256 + f] = s;
}

// ---------- fused front-end: prep_w | bhist | xbar (atil from prior kernel)
__global__ __launch_bounds__(256) void k_front(const float* __restrict__ x,
                                               const float* __restrict__ W,
                                               unsigned short* __restrict__ Wt,
                                               const float* __restrict__ atil,
                                               unsigned short* __restrict__ xb,
                                               float* __restrict__ eAr,
                                               const int* __restrict__ src,
                                               int* __restrict__ M,
                                               int E, int NB){
  __shared__ int hh[NBK];
  const int tid = threadIdx.x;
  const int bid = blockIdx.x;
  if (bid < 8){
    const int r = tid>>2, cb = (tid&3)*64;
    char* tile = (char*)(Wt + (size_t)bid*16384);
    const float* Wr = W + ((long)bid*64 + r)*INF;
#pragma unroll
    for (int i=0;i<16;i++){
      int c = cb + i*4;
      float4 v = *(const float4*)(Wr + c);
      ushort4 b; b.x=f2bf(v.x); b.y=f2bf(v.y); b.z=f2bf(v.z); b.w=f2bf(v.w);
      int addr = r*512 + ((((c>>3) ^ (r&7)))<<4) + ((c&7)<<1);
      *(ushort4*)(tile + addr) = b;
    }
    return;
  }
  if (bid < 8+NB){
    const int b = bid-8;
    for (int i=tid;i<NBK;i+=256) hh[i]=0;
    __syncthreads();
    const int base = b*EPB;
    const int lim = min(E-base, EPB);
    for (int i=tid;i<lim;i+=256) atomicAdd(&hh[src[base+i]>>7], 1);
    __syncthreads();
    for (int i=tid;i<NBK;i+=256) M[(long)i*NB + b] = hh[i];
    return;
  }
  const int w = tid>>6, l = tid&63;
  const long n = (long)(bid-8-NB)*4 + w;
  if (n > NN) return;
  if (n == NN){
    uint2 z; z.x=0; z.y=0;
    *(uint2*)((char*)xb + (size_t)n*512 + l*8) = z;
    if (l < 8) eAr[n*NH + l] = 0.f;
    return;
  }
  float4 v = *(const float4*)(x + n*INF + l*4);
  uint2 d;
  d.x = (unsigned)f2bf(v.x) | ((unsigned)f2bf(v.y)<<16);
  d.y = (unsigned)f2bf(v.z) | ((unsigned)f2bf(v.w)<<16);
  *(uint2*)((char*)xb + (size_t)n*512 + l*8) = d;
  float p[8];
#pragma unroll
  for (int h=0;h<8;h++){
    float4 a = *(const float4*)(atil + h*256 + l*4);
    p[h] = v.x*a.x + v.y*a.y + v.z*a.z + v.w*a.w;
  }
#pragma unroll
  for (int off=1; off<64; off<<=1){
#pragma unroll
    for (int h=0;h<8;h++) p[h] += __shfl_xor(p[h], off, 64);
  }
  if (l < 8){
    float e = p[0];
#pragma unroll
    for (int h=1;h<8;h++) if (l==h) e = p[h];
    eAr[n*NH + l] = __expf(e);
  }
}

// per-bucket exclusive scan over blocks (in place) + bucket totals
__global__ __launch_bounds__(256) void k_bscan(int* __restrict__ M,
                                               int* __restrict__ tot, int NB){
  __shared__ int lds[256];
  const int k = blockIdx.x, tid = threadIdx.x;
  int v = (tid<NB) ? M[(long)k*NB+tid] : 0;
  const int orig = v;
  lds[tid]=v; __syncthreads();
  for (int off=1; off<256; off<<=1){
    int a = (tid>=off)? lds[tid-off] : 0;
    __syncthreads(); lds[tid]+=a; __syncthreads();
  }
  if (tid<NB) M[(long)k*NB+tid] = lds[tid]-orig;
  if (tid==255) tot[k] = lds[255];
}

// generic small exclusive scan (n < 512), out[0..n], out[n]=total
__global__ __launch_bounds__(512) void k_sscan(const int* __restrict__ in,
                                               int* __restrict__ out, int n){
  __shared__ int lds[512];
  const int tid = threadIdx.x;
  int v = (tid<n)? in[tid] : 0;
  const int orig = v;
  lds[tid]=v; __syncthreads();
  for (int off=1; off<512; off<<=1){
    int a = (tid>=off)? lds[tid-off] : 0;
    __syncthreads(); lds[tid]+=a; __syncthreads();
  }
  if (tid<=n) out[tid] = lds[tid]-orig;
}

// bucket scatter of (src,dst) via LDS cursors — u32 payload: dst<<7 | src&127
__global__ __launch_bounds__(256) void k_bscat(const int* __restrict__ src,
                                               const int* __restrict__ dst,
                                               const int* __restrict__ M,
                                               const int* __restrict__ bOff,
                                               unsigned* __restrict__ ebuf,
                                               int E, int NB){
  __shared__ int cur[NBK];
  const int tid = threadIdx.x, b = blockIdx.x;
  for (int i=tid;i<NBK;i+=256) cur[i] = bOff[i] + M[(long)i*NB + b];
  __syncthreads();
  const int base = b*EPB;
  const int lim = min(E-base, EPB);
  for (int i=tid;i<lim;i+=256){
    int s = src[base+i], d = dst[base+i];
    int p = atomicAdd(&cur[s>>7], 1);
    ebuf[p] = ((unsigned)d<<7) | (unsigned)(s&127);
  }
}

// per-bucket node counts + padded(8) bucket total
__global__ __launch_bounds__(256) void k_bcnt2(const unsigned* __restrict__ ebuf,
                                               const int* __restrict__ bOff,
                                               int* __restrict__ cnt,
                                               int* __restrict__ pbTot){
  __shared__ int h[128];
  __shared__ int ps[128];
  const int k = blockIdx.x, tid = threadIdx.x;
  if (tid<128) h[tid]=0;
  __syncthreads();
  const int beg = bOff[k], end = bOff[k+1];
  for (int i=beg+tid; i<end; i+=256)
    atomicAdd(&h[(int)(ebuf[i] & 127u)], 1);
  __syncthreads();
  if (tid<128){
    cnt[(k<<7)+tid] = h[tid];
    ps[tid] = (h[tid]+7)&~7;
  }
  __syncthreads();
  for (int off=64; off>0; off>>=1){
    if (tid<off) ps[tid] += ps[tid+off];
    __syncthreads();
  }
  if (tid==0) pbTot[k] = ps[0];
}

// finalize: row_ptr + scatter + padfill per bucket
__global__ __launch_bounds__(256) void k_final(const unsigned* __restrict__ ebuf,
                                               const int* __restrict__ bOff,
                                               const int* __restrict__ cnt,
                                               const int* __restrict__ pbOff,
                                               int* __restrict__ row_ptr,
                                               int* __restrict__ col){
  __shared__ int s[128];
  __shared__ int cur[128];
  __shared__ int pend[128];
  const int k = blockIdx.x, tid = threadIdx.x;
  int c = 0, pc = 0;
  if (tid<128){
    c = cnt[(k<<7)+tid];
    pc = (c+7)&~7;
    s[tid] = pc;
  }
  __syncthreads();
  for (int off=1; off<128; off<<=1){
    int a = (tid>=off && tid<128)? s[tid-off] : 0;
    __syncthreads();
    if (tid<128) s[tid] += a;
    __syncthreads();
  }
  const int base = pbOff[k];
  if (tid<128){
    int rp = base + s[tid] - pc;
    row_ptr[(k<<7)+tid] = rp;
    cur[tid] = rp;
    pend[tid] = rp + pc;
  }
  __syncthreads();
  const int beg = bOff[k], end = bOff[k+1];
  for (int i=beg+tid; i<end; i+=256){
    unsigned e = ebuf[i];
    int p = atomicAdd(&cur[e & 127u], 1);
    col[p] = (int)(e>>7);
  }
  __syncthreads();
  if (tid<128){
    for (int i=cur[tid]; i<pend[tid]; i++) col[i] = NN;  // sentinel
  }
}

// ---------------- aggregation: half-row waves (2 waves/node), packed FMA
// g stored NATURAL row-major: [tile][h (32KB)][row r (512B)][feature f (2B)]
__global__ __launch_bounds__(256) void k_aggr2(const int* __restrict__ row_ptr,
                                               const int* __restrict__ col,
                                               const unsigned short* __restrict__ xb,
                                               const float* __restrict__ eAr,
                                               unsigned short* __restrict__ g,
                                               float* __restrict__ den,
                                               int tile0){
  const int tid = threadIdx.x, l = tid&63;
  const int wv = tid>>6;               // 0..3
  const int fh = wv&1;                 // feature half
  const long n = (long)tile0*64 + blockIdx.x*2 + (wv>>1);
  if (n >= NN) return;
  const int beg = __builtin_amdgcn_readfirstlane(row_ptr[n]);
  const int end = __builtin_amdgcn_readfirstlane(row_ptr[n+1]);
  const char* xbp = (const char*)xb + fh*256;
  v2f acc[8] = {};
  float dnl = 0.f;
  const long l4 = (long)l*4;
  const int lw = l&7;

  for (int i=beg; i<end; i+=8){
    int cc[8];
#pragma unroll
    for (int e=0;e<8;e++) cc[e] = __builtin_amdgcn_readfirstlane(col[i+e]);
    unsigned q[8];
#pragma unroll
    for (int e=0;e<8;e++) q[e] = *(const unsigned*)(xbp + (size_t)cc[e]*512 + l4);
    float wl[8];
#pragma unroll
    for (int e=0;e<8;e++) wl[e] = eAr[(size_t)cc[e]*NH + lw];
#pragma unroll
    for (int e=0;e<8;e++) dnl += wl[e];
#pragma unroll
    for (int e=0;e<8;e++){
      f32x8 wv8 = *(const f32x8*)(eAr + (size_t)cc[e]*NH);
      v2f f01;
      f01.x = __uint_as_float(q[e]<<16);
      f01.y = __uint_as_float(q[e]&0xffff0000u);
#pragma unroll
      for (int h=0;h<8;h++){
        v2f w2; w2.x = wv8[h]; w2.y = wv8[h];
        acc[h] = __builtin_elementwise_fma(w2, f01, acc[h]);
      }
    }
  }

  // natural-layout write: wave writes 256B contiguous per head (full lines)
  const int lt = (int)(n>>6) - tile0;
  const int r  = (int)(n&63);
  char* tb = (char*)g + (size_t)lt*262144 + r*512 + fh*256 + l*4;
#pragma unroll
  for (int h=0;h<8;h++){
    unsigned d = (unsigned)f2bf(acc[h].x) | ((unsigned)f2bf(acc[h].y)<<16);
    *(unsigned*)(tb + h*32768) = d;
  }
  if (fh==0 && l < 8) den[n*NH + l] = dnl;
}

// ---------------- per-head GEMM: out[n, h*64+o] = elu( (g_h[n] . W_h[o]) / den )
// g is natural layout; swizzle applied on the per-lane GLOBAL source address
// (linear LDS dest, m173 pattern) so the LDS image matches the ds_read pattern.
__global__ __launch_bounds__(256) void k_gemm2(const unsigned short* __restrict__ g,
                                               const unsigned short* __restrict__ Wt,
                                               const float* __restrict__ den,
                                               float* __restrict__ out,
                                               int tile0){
  __shared__ unsigned short As[16384];
  __shared__ unsigned short Bs[16384];
  __shared__ float linv[64];
  const int tid = threadIdx.x, w = tid>>6, l = tid&63;
  const int brow = tile0 + blockIdx.x;
  const int h = blockIdx.y;
  {
    const char* gb = (const char*)g + (size_t)blockIdx.x*262144 + h*32768;
    char* dstA = (char*)As + w*8192;
#pragma unroll
    for (int k=0;k<8;k++){
      int r = w*16 + k*2 + (l>>5);                     // LDS row this lane fills
      const char* sA = gb + r*512 + (((l&31) ^ (r&7))<<4);  // inverse-swizzled src
      GLOAD_LDS16(sA, dstA + k*1024);
    }
    const char* srcB = (const char*)Wt + (size_t)h*32768 + w*8192 + l*16;
    char* dstB = (char*)Bs + w*8192;
#pragma unroll
    for (int k=0;k<8;k++) GLOAD_LDS16(srcB + k*1024, dstB + k*1024);
  }
  if (tid < 64){
    long gr = (long)brow*64 + tid;
    float dv = (gr < NN) ? den[gr*NH + h] : 1.f;
    linv[tid] = dv > 0.f ? 1.f/dv : 0.f;
  }
  asm volatile("s_waitcnt vmcnt(0)");
  __syncthreads();

  const int col = w*16 + (l&15);
  f32x4 acc[4] = {};
#pragma unroll
  for (int ks=0; ks<8; ks++){
    int chunkB = (ks*4 + (l>>4)) ^ (col&7);
    bf16x8 bfrag = *(const bf16x8*)((char*)Bs + col*512 + (chunkB<<4));
#pragma unroll
    for (int mt=0; mt<4; mt++){
      int ar_ = mt*16 + (l&15);
      int chunkA = (ks*4 + (l>>4)) ^ (ar_&7);
      bf16x8 afrag = *(const bf16x8*)((char*)As + ar_*512 + (chunkA<<4));
      acc[mt] = __builtin_amdgcn_mfma_f32_16x16x32_bf16(afrag, bfrag, acc[mt], 0,0,0);
    }
  }
#pragma unroll
  for (int mt=0; mt<4; mt++){
#pragma unroll
    for (int j=0;j<4;j++){
      int r = mt*16 + (l>>4)*4 + j;
      long gr = (long)brow*64 + r;
      if (gr < NN){
        float v = acc[mt][j] * linv[r];
        out[gr*NC + h*64 + col] = v>0.f ? v : expm1f(v);
      }
    }
  }
}

extern "C" void kernel_launch(void* const* d_in, const int* in_sizes, int n_in,
                              void* d_out, int out_size, void* d_ws, size_t ws_size,
                              hipStream_t stream){
  const float* x   = (const float*)d_in[0];
  const int*   src = (const int*)d_in[1];
  const int*   dst = (const int*)d_in[2];
  const float* Ws  = (const float*)d_in[3];
  const float* Av  = (const float*)d_in[4];
  const int E = in_sizes[1];
  const int NB = (E + EPB - 1) / EPB;

  char* ws = (char*)d_ws;
  size_t off = 0;
  auto alloc = [&](size_t bytes)->void*{
    void* p = ws + off; off += (bytes + 255) & ~(size_t)255; return p;
  };
  unsigned short* xb   = (unsigned short*)alloc((size_t)50048*512);
  float* eAr           = (float*)alloc((size_t)50048*NH*4);
  float* atil          = (float*)alloc(8*256*4);
  float* den           = (float*)alloc((size_t)50048*NH*4);
  unsigned short* Wt   = (unsigned short*)alloc((size_t)8*32768);
  int*   cnt           = (int*)alloc(50304*4);
  int*   row_ptr       = (int*)alloc(50304*4);
  int*   M             = (int*)alloc((size_t)NBK*256*4);
  int*   tot           = (int*)alloc(512*4);
  int*   bOff          = (int*)alloc(512*4);
  int*   pbTot         = (int*)alloc(512*4);
  int*   pbOff         = (int*)alloc(512*4);
  int*   col           = (int*)alloc(((size_t)E + 8*50048 + 64)*4);

  size_t remain = (ws_size > off + 256) ? (ws_size - off - 256) : 0;
  int chunk = (int)(remain / 262144);
  if (chunk > NTILES) chunk = NTILES;
  if (chunk < 25) chunk = 25;            // ebuf (E*4 bytes) must fit in g alias
  unsigned short* g = (unsigned short*)alloc((size_t)chunk*262144);
  unsigned* ebuf = (unsigned*)g;         // dead before first g write

  k_atil<<<8,256,0,stream>>>(Ws, Av, atil);
  k_front<<<8+NB+NBX,256,0,stream>>>(x, Ws, Wt, atil, xb, eAr, src, M, E, NB);
  k_bscan<<<NBK,256,0,stream>>>(M, tot, NB);
  k_sscan<<<1,512,0,stream>>>(tot, bOff, NBK);
  k_bscat<<<NB,256,0,stream>>>(src, dst, M, bOff, ebuf, E, NB);
  k_bcnt2<<<NBK,256,0,stream>>>(ebuf, bOff, cnt, pbTot);
  k_sscan<<<1,512,0,stream>>>(pbTot, pbOff, NBK);
  k_final<<<NBK,256,0,stream>>>(ebuf, bOff, cnt, pbOff, row_ptr, col);

  int tile0 = 0;
  while (tile0 < NTILES){
    int tiles = NTILES - tile0 < chunk ? NTILES - tile0 : chunk;
    k_aggr2<<<tiles*32,256,0,stream>>>(row_ptr, col, xb, eAr, g, den, tile0);
    k_gemm2<<<dim3(tiles,8),256,0,stream>>>(g, Wt, den, (float*)d_out, tile0);
    tile0 += tiles;
  }
}